// Round 12
// baseline (672.950 us; speedup 1.0000x reference)
//
#include <hip/hip_runtime.h>
#include <hip/hip_bf16.h>

// GCN 3-layer: gcn_norm -> (GCNConv, ELU) x2 -> GCNConv
// N=100000, E=3200000, dims 128->32->64->128.
// agg is linear => aggregate in the SMALLER feature dim per layer.
//
// CSR build: bucketed 2-level counting sort (k_hist -> k_bscan ->
// k_scatter -> k_nodecnt -> k_fill).
// epk[e] = src(17b) | q15(dinv[src]*ew)<<17  (4B/edge, precomputed w').
//
// LESSONS:
//  - r2: LDS f32 atomicAdd agg = 12x slower. Never E*F-scale ds_add.
//  - r3: agg near compulsory-traffic ceiling; bytes are the lever.
//  - r4: bf16 intermediate buffers (storage only, fp32 accum) -> -93us.
//  - r5/r6: scatter fixed via batch-load-then-process + 782 blocks.
//  - r8: dinv[src] inside agg loop = wash; keep hot loops minimal.
//  - r9: 4B epk w/ precomputed q15(dinv*ew): aggs off the top.
//  - r10/r11: GEMM bank-conflict map swap + KC chunking: 57->~<45us.
//  - r12 (this): agg64 was co-limited: VALU 52% (=26us arithmetic) and
//    102MB of per-XCD H re-streaming (H 12.8MB >> 4MB L2/XCD). Fix the
//    memory half: CHUNK-MAJOR feature layout (8 planes); agg block
//    chunk = blockIdx&7 -> each XCD touches one 1.6MB plane, fully
//    L2-resident; gathers become L2 hits; only epk re-stream (L3,
//    sequential) misses L2. Perf-only use of blockIdx%8->XCD mapping.
// Inputs: fp32 (probed vs bf16), edge_index i64 (probed vs i32). Output fp32.

constexpr int N = 100000;
constexpr int E = 3200000;

constexpr int BSHIFT = 7;
constexpr int BSIZE = 128;                       // nodes per bucket
constexpr int NBKT = (N + BSIZE - 1) / BSIZE;    // 782

constexpr float FIX_SCALE = 16777216.0f;         // 2^24
constexpr float Q15 = 32768.0f;

constexpr int HIST_EPB = 4096;                   // edges per block, hist
constexpr int SC_EPB = 4096;                     // edges per block, scatter

__device__ __forceinline__ float ldf(const void* p, int isbf, size_t i) {
    return isbf ? __bfloat162float(((const __hip_bfloat16*)p)[i])
                : ((const float*)p)[i];
}

__device__ __forceinline__ int ld_idx(const void* ei, int is64, size_t pos) {
    return is64 ? (int)((const long long*)ei)[pos] : ((const int*)ei)[pos];
}

// --- bf16x4 pack/unpack (manual RNE, no API dependence) ---
__device__ __forceinline__ float4 bf4tof4(uint2 u) {
    float4 r;
    r.x = __uint_as_float(u.x << 16);
    r.y = __uint_as_float(u.x & 0xffff0000u);
    r.z = __uint_as_float(u.y << 16);
    r.w = __uint_as_float(u.y & 0xffff0000u);
    return r;
}
__device__ __forceinline__ unsigned short f2bf(float f) {
    unsigned u = __float_as_uint(f);
    unsigned rnd = 0x7fffu + ((u >> 16) & 1u);
    return (unsigned short)((u + rnd) >> 16);
}
__device__ __forceinline__ unsigned packbf2(float a, float b) {
    return (unsigned)f2bf(a) | ((unsigned)f2bf(b) << 16);
}
__device__ __forceinline__ uint2 f4tobf4(float4 v) {
    uint2 r;
    r.x = packbf2(v.x, v.y);
    r.y = packbf2(v.z, v.w);
    return r;
}

// flags[0] = is64 (edge_index), flags[1] = isbf (float tensors)
// also zeroes the bucket-count array (runs before k_hist on the stream)
__global__ void k_probe(const void* ei, const void* x, int* flags, int* bkt_cnt) {
    __shared__ int bad64, bigcnt;
    int t = threadIdx.x;
    if (t == 0) { bad64 = 0; bigcnt = 0; }
    __syncthreads();
    long long v = ((const long long*)ei)[t];
    if (v < 0 || v >= (long long)N) atomicAdd(&bad64, 1);
    const unsigned short* u = (const unsigned short*)x;
    int big = 0;
    for (int i = t * 16; i < t * 16 + 16; i++) {
        int e = (u[i] >> 7) & 0xFF;
        if (e >= 133) big++;
    }
    atomicAdd(&bigcnt, big);
    for (int i = t; i < NBKT; i += 256) bkt_cnt[i] = 0;
    __syncthreads();
    if (t == 0) { flags[0] = (bad64 == 0) ? 1 : 0; flags[1] = (bigcnt < 40) ? 1 : 0; }
}

// bucket histogram: batch-load targets into registers, then LDS atomics,
// one global atomic per (block,bucket)
__global__ __launch_bounds__(512) void k_hist(const void* ei, const int* flags,
                                              int* bkt_cnt) {
    constexpr int EPT = HIST_EPB / 512;          // 8
    __shared__ int h[NBKT];
    int t = threadIdx.x;
    for (int i = t; i < NBKT; i += 512) h[i] = 0;
    __syncthreads();
    int is64 = flags[0];
    size_t eb = (size_t)blockIdx.x * HIST_EPB;
    int nb = (int)min((size_t)HIST_EPB, (size_t)E - eb);
    int cc[EPT];
#pragma unroll
    for (int k = 0; k < EPT; k++) {
        int idx = t + k * 512;
        cc[k] = (idx < nb) ? ld_idx(ei, is64, (size_t)E + eb + idx) : -1;
    }
#pragma unroll
    for (int k = 0; k < EPT; k++)
        if (cc[k] >= 0) atomicAdd(&h[cc[k] >> BSHIFT], 1);
    __syncthreads();
    for (int i = t; i < NBKT; i += 512) {
        int v = h[i];
        if (v) atomicAdd(&bkt_cnt[i], v);
    }
}

// single-block exclusive scan over NBKT buckets -> bkt_off, bkt_cur
__global__ void k_bscan(const int* bkt_cnt, int* bkt_off, int* bkt_cur) {
    __shared__ int s[256];
    int t = threadIdx.x;
    int v[4]; int sum = 0;
#pragma unroll
    for (int j = 0; j < 4; j++) {
        int i = t * 4 + j;
        v[j] = (i < NBKT) ? bkt_cnt[i] : 0;
        sum += v[j];
    }
    s[t] = sum; __syncthreads();
    for (int st = 1; st < 256; st <<= 1) {
        int add = (t >= st) ? s[t - st] : 0;
        __syncthreads();
        s[t] += add;
        __syncthreads();
    }
    int excl = s[t] - sum;
#pragma unroll
    for (int j = 0; j < 4; j++) {
        int i = t * 4 + j;
        if (i < NBKT) { bkt_off[i] = excl; bkt_cur[i] = excl; excl += v[j]; }
    }
    if (t == 0) bkt_off[NBKT] = E;
}

// bucket-sort edges into tmp[]: batch-load (r,c,w) into registers ONCE,
// then per-block LDS histogram + run reservation + placement, all from
// registers. tmp entry: .x = r | (c&127)<<17  (r<2^17), .y = w bits
__global__ __launch_bounds__(512) void k_scatter(const void* ei, const int* flags,
                                                 const void* ew, int* bkt_cur,
                                                 int2* tmp) {
    constexpr int EPT = SC_EPB / 512;            // 8
    __shared__ int h[NBKT];
    __shared__ int base_s[NBKT];
    int t = threadIdx.x;
    for (int i = t; i < NBKT; i += 512) h[i] = 0;
    __syncthreads();
    int is64 = flags[0], isbf = flags[1];
    size_t eb = (size_t)blockIdx.x * SC_EPB;
    int nb = (int)min((size_t)SC_EPB, (size_t)E - eb);
    int rr[EPT], cc[EPT]; float ww[EPT];
    // batched, coalesced, independent loads; single drain
#pragma unroll
    for (int k = 0; k < EPT; k++) {
        int idx = t + k * 512;
        if (idx < nb) {
            size_t e = eb + idx;
            rr[k] = ld_idx(ei, is64, e);
            cc[k] = ld_idx(ei, is64, (size_t)E + e);
            ww[k] = ldf(ew, isbf, e);
        } else {
            rr[k] = 0; cc[k] = -1; ww[k] = 0.f;
        }
    }
    // pass 1: local histogram (registers -> LDS atomics, pipelined)
#pragma unroll
    for (int k = 0; k < EPT; k++)
        if (cc[k] >= 0) atomicAdd(&h[cc[k] >> BSHIFT], 1);
    __syncthreads();
    // reserve a dense run per bucket
    for (int i = t; i < NBKT; i += 512) {
        int v = h[i];
        base_s[i] = v ? atomicAdd(&bkt_cur[i], v) : 0;
    }
    __syncthreads();
    for (int i = t; i < NBKT; i += 512) h[i] = 0;
    __syncthreads();
    // pass 2: place edges within reserved runs (registers -> global)
#pragma unroll
    for (int k = 0; k < EPT; k++) {
        if (cc[k] >= 0) {
            int b = cc[k] >> BSHIFT;
            int loc = atomicAdd(&h[b], 1);
            int pos = base_s[b] + loc;
            tmp[pos] = make_int2(rr[k] | ((cc[k] & (BSIZE - 1)) << 17),
                                 __float_as_int(ww[k]));
        }
    }
}

// per bucket: node counts + fixed-point weight sums (LDS int atomics),
// 128-wide LDS scan -> offsets; dinv = rsqrt(1 + wsum) (bit-identical
// to the original packed scheme)
__global__ __launch_bounds__(256) void k_nodecnt(const int2* __restrict__ tmp,
                                                 const int* __restrict__ bkt_off,
                                                 int* __restrict__ counts,
                                                 int* __restrict__ offsets,
                                                 float* __restrict__ dinv) {
    __shared__ int cnt_s[BSIZE];
    __shared__ unsigned int wfx_s[BSIZE];
    __shared__ int sc_s[BSIZE];
    int t = threadIdx.x;
    int b = blockIdx.x;
    if (t < BSIZE) { cnt_s[t] = 0; wfx_s[t] = 0u; }
    __syncthreads();
    int s0 = bkt_off[b], s1 = bkt_off[b + 1];
    for (int p = s0 + t; p < s1; p += 256) {
        int2 ev = tmp[p];
        int c7 = (int)(((unsigned)ev.x) >> 17);
        float w = __int_as_float(ev.y);
        atomicAdd(&cnt_s[c7], 1);
        atomicAdd(&wfx_s[c7], (unsigned)__float2uint_rn(w * FIX_SCALE));
    }
    __syncthreads();
    if (t < BSIZE) sc_s[t] = cnt_s[t];
    __syncthreads();
    for (int st = 1; st < BSIZE; st <<= 1) {
        int add = (t < BSIZE && t >= st) ? sc_s[t - st] : 0;
        __syncthreads();
        if (t < BSIZE) sc_s[t] += add;
        __syncthreads();
    }
    if (t < BSIZE) {
        int node = b * BSIZE + t;
        if (node < N) {
            int c = cnt_s[t];
            offsets[node] = s0 + sc_s[t] - c;   // bucket base + exclusive
            counts[node] = c;
            float deg = 1.0f + (float)wfx_s[t] * (1.0f / FIX_SCALE);
            dinv[node] = rsqrtf(deg);
        }
    }
}

// per bucket: fill 4B CSR epk[pos] = src | q15(dinv[src]*ew)<<17.
__global__ __launch_bounds__(256) void k_fill(const int2* __restrict__ tmp,
                                              const int* __restrict__ bkt_off,
                                              const int* __restrict__ offsets,
                                              const float* __restrict__ dinv,
                                              unsigned* __restrict__ epk) {
    __shared__ int lcur[BSIZE];
    int t = threadIdx.x;
    int b = blockIdx.x;
    if (t < BSIZE) {
        int node = b * BSIZE + t;
        lcur[t] = (node < N) ? offsets[node] : 0;
    }
    __syncthreads();
    int s0 = bkt_off[b], s1 = bkt_off[b + 1];
    for (int p = s0 + t; p < s1; p += 256) {
        int2 ev = tmp[p];
        unsigned px = (unsigned)ev.x;
        int r = (int)(px & 0x1FFFFu);
        int c7 = (int)(px >> 17);
        float w = __int_as_float(ev.y);
        float nr = dinv[r] * w;
        unsigned q = __float2uint_rn(nr * Q15);
        if (q > 32767u) q = 32767u;
        int pos = atomicAdd(&lcur[c7], 1);
        epk[pos] = (unsigned)r | (q << 17);
    }
}

// --- register-blocked GEMM: H[N,FOUT] = X[N,FIN] @ W[FIN,FOUT] (+b, ELU)
// XMODE: 1 = external input (row-major fp32/bf16 probe), 2 = internal
// CHUNK-MAJOR bf16 (8 planes of FIN/8 features). OBF: write chunk-major
// bf16 (8 planes of FOUT/8 features) vs fp32 row-major (final output).
// KC k-chunked staging; trow=t%TROWS map (bank-conflict-free, r10).
template <int FIN, int FOUT, int TM, int TN, int KC, int XMODE, bool OBF,
          bool BIAS, bool ELU>
__global__ __launch_bounds__(256) void k_gemm(const void* __restrict__ X,
                                              const void* __restrict__ W,
                                              const void* __restrict__ bias,
                                              const int* __restrict__ flags,
                                              void* __restrict__ H) {
    static_assert(!OBF || TN == 4, "chunk-major write assumes TN==4");
    constexpr int TCOLS = FOUT / TN;
    constexpr int TROWS = 256 / TCOLS;
    constexpr int BR = TROWS * TM;
    __shared__ float wl[KC * FOUT];
    __shared__ float xt[KC][BR + 1];
    int t = threadIdx.x;
    int isbf = flags[1];
    int base = blockIdx.x * BR;
    int trow = t % TROWS, tcol = t / TROWS;   // bank-conflict-free map
    int r0 = trow * TM, c0 = tcol * TN;
    float acc[TM][TN] = {};

    for (int kc = 0; kc < FIN; kc += KC) {
        if (kc) __syncthreads();              // previous chunk fully read
        // stage W rows [kc, kc+KC)
        if (!isbf) {
            const float4* W4 = (const float4*)W;
            float4* wl4 = (float4*)wl;
            for (int i = t; i < KC * FOUT / 4; i += 256)
                wl4[i] = W4[(size_t)kc * FOUT / 4 + i];
        } else {
            for (int i = t; i < KC * FOUT; i += 256)
                wl[i] = __bfloat162float(((const __hip_bfloat16*)W)[(size_t)kc * FOUT + i]);
        }
        // stage X columns [kc, kc+KC), transposed into xt[k][row]
        if (XMODE == 2) {
            // chunk-major bf16: plane q/UPCI holds uint2 slot q%UPCI
            const uint2* X2 = (const uint2*)X;
            constexpr int UPCI = FIN / 32;    // uint2/node/plane (1 or 2)
            for (int i = t; i < BR * KC / 4; i += 256) {
                int kq = i / BR;              // kq-major -> coalesced
                int row = i % BR;
                int node = base + row;
                int q = kc / 4 + kq;          // global uint2 index
                uint2 u = make_uint2(0u, 0u);
                if (node < N)
                    u = X2[((size_t)(q / UPCI) * N + node) * UPCI + (q % UPCI)];
                float4 v = bf4tof4(u);
                int k = kq * 4;
                xt[k][row] = v.x; xt[k + 1][row] = v.y;
                xt[k + 2][row] = v.z; xt[k + 3][row] = v.w;
            }
        } else if (!isbf) {
            const float4* X4 = (const float4*)X;
            for (int i = t; i < BR * KC / 4; i += 256) {
                int row = i / (KC / 4);
                int kq = i % (KC / 4);
                int node = base + row;
                float4 v = make_float4(0.f, 0.f, 0.f, 0.f);
                if (node < N) v = X4[(size_t)node * (FIN / 4) + kc / 4 + kq];
                int k = kq * 4;
                xt[k][row] = v.x; xt[k + 1][row] = v.y;
                xt[k + 2][row] = v.z; xt[k + 3][row] = v.w;
            }
        } else {
            for (int i = t; i < BR * KC; i += 256) {
                int row = i / KC, k = i % KC;
                int node = base + row;
                float v = (node < N)
                    ? __bfloat162float(((const __hip_bfloat16*)X)[(size_t)node * FIN + kc + k])
                    : 0.f;
                xt[k][row] = v;
            }
        }
        __syncthreads();

#pragma unroll 4
        for (int k = 0; k < KC; k++) {
            float a[TM], b[TN];
#pragma unroll
            for (int m = 0; m < TM; m++) a[m] = xt[k][r0 + m];
#pragma unroll
            for (int n = 0; n < TN; n++) b[n] = wl[k * FOUT + c0 + n];
#pragma unroll
            for (int m = 0; m < TM; m++)
#pragma unroll
                for (int n = 0; n < TN; n++) acc[m][n] += a[m] * b[n];
        }
    }

#pragma unroll
    for (int m = 0; m < TM; m++) {
        int node = base + r0 + m;
        if (node >= N) continue;
        float vv[TN];
#pragma unroll
        for (int n = 0; n < TN; n++) {
            float v = acc[m][n];
            if (BIAS) v += ldf(bias, isbf, c0 + n);
            if (ELU) v = (v > 0.0f) ? v : expm1f(v);
            vv[n] = v;
        }
        if (OBF) {
            // chunk-major: plane c0/FPCO, uint2 slot (c0%FPCO)/4
            constexpr int FPCO = FOUT / 8;
            constexpr int UPCO = FOUT / 32;
            uint2* H2 = (uint2*)H;
            uint2 val = make_uint2(packbf2(vv[0], vv[1]), packbf2(vv[2], vv[3]));
            H2[((size_t)(c0 / FPCO) * N + node) * UPCO + ((c0 % FPCO) >> 2)] = val;
        } else {
            float* Hrow = (float*)H + (size_t)node * FOUT + c0;
#pragma unroll
            for (int n = 0; n < TN; n += 4)
                *(float4*)(Hrow + n) = make_float4(vv[n], vv[n + 1], vv[n + 2], vv[n + 3]);
        }
    }
}

// --- XCD-chunked aggregation: out[n] = di*Σ_e w'_e*H[src_e] + di^2*H[n]
// (+b, ELU). Feature dim split into 8 chunk planes; block's chunk =
// blockIdx&7 -> each XCD touches ONE plane (0.8/1.6MB, L2-resident) so
// the random gathers are L2 hits; only the sequential epk re-stream
// misses L2 (L3-served). epk 4B/edge: src(17b) | q15(w')<<17.
// fp32 accumulation; unroll 8 + software pipeline.
template <int F, bool BIAS, bool ELU>
__global__ __launch_bounds__(256) void k_agg(const uint2* __restrict__ Hb,
                                             const int* __restrict__ offsets,
                                             const int* __restrict__ counts,
                                             const unsigned* __restrict__ epk,
                                             const float* __restrict__ dinv,
                                             const void* __restrict__ bias,
                                             const int* __restrict__ flags,
                                             uint2* __restrict__ outb) {
    constexpr int FPC = F / 8;        // features per chunk (4 or 8)
    constexpr int UPC = F / 32;       // uint2 per node per chunk (1 or 2)
    constexpr int NPB = 256 / UPC;    // nodes per block (256 or 128)
    constexpr float QS = 1.0f / Q15;
    int t = threadIdx.x;
    int chunk = blockIdx.x & 7;
    int lane = t % UPC;
    int g = t / UPC;
    int node = (blockIdx.x >> 3) * NPB + g;
    if (node >= N) return;
    const uint2* Hp = Hb + (size_t)chunk * N * UPC;
    uint2* Op = outb + (size_t)chunk * N * UPC;
    float di = dinv[node];
    float4 h = bf4tof4(Hp[(size_t)node * UPC + lane]);
    float4 acc0 = make_float4(0.f, 0.f, 0.f, 0.f);
    float4 acc1 = make_float4(0.f, 0.f, 0.f, 0.f);
    int p = offsets[node];
    int pend = p + counts[node];

    unsigned eA[8];
    bool have = (p + 8 <= pend);
    if (have) {
#pragma unroll
        for (int j = 0; j < 8; j++) eA[j] = epk[p + j];
    }
    while (have) {
        // issue 8 independent L2-hit gathers
        uint2 gg[8];
#pragma unroll
        for (int j = 0; j < 8; j++)
            gg[j] = Hp[(size_t)(eA[j] & 0x1FFFFu) * UPC + lane];
        float w[8];
#pragma unroll
        for (int j = 0; j < 8; j++) w[j] = (float)(eA[j] >> 17) * QS;
        p += 8;
        bool nxt = (p + 8 <= pend);
        unsigned eB[8];
        if (nxt) {
#pragma unroll
            for (int j = 0; j < 8; j++) eB[j] = epk[p + j];
        }
#pragma unroll
        for (int j = 0; j < 8; j += 2) {
            float4 g0 = bf4tof4(gg[j]);
            float4 g1 = bf4tof4(gg[j + 1]);
            acc0.x += g0.x * w[j]; acc0.y += g0.y * w[j];
            acc0.z += g0.z * w[j]; acc0.w += g0.w * w[j];
            acc1.x += g1.x * w[j + 1]; acc1.y += g1.y * w[j + 1];
            acc1.z += g1.z * w[j + 1]; acc1.w += g1.w * w[j + 1];
        }
#pragma unroll
        for (int j = 0; j < 8; j++) eA[j] = eB[j];
        have = nxt;
    }
    // tail: 4-wide then scalar
    for (; p + 4 <= pend; p += 4) {
        unsigned e0 = epk[p], e1 = epk[p + 1], e2 = epk[p + 2], e3 = epk[p + 3];
        float4 h0 = bf4tof4(Hp[(size_t)(e0 & 0x1FFFFu) * UPC + lane]);
        float4 h1 = bf4tof4(Hp[(size_t)(e1 & 0x1FFFFu) * UPC + lane]);
        float4 h2 = bf4tof4(Hp[(size_t)(e2 & 0x1FFFFu) * UPC + lane]);
        float4 h3 = bf4tof4(Hp[(size_t)(e3 & 0x1FFFFu) * UPC + lane]);
        float w0 = (float)(e0 >> 17) * QS;
        float w1 = (float)(e1 >> 17) * QS;
        float w2 = (float)(e2 >> 17) * QS;
        float w3 = (float)(e3 >> 17) * QS;
        acc0.x += h0.x * w0 + h2.x * w2; acc1.x += h1.x * w1 + h3.x * w3;
        acc0.y += h0.y * w0 + h2.y * w2; acc1.y += h1.y * w1 + h3.y * w3;
        acc0.z += h0.z * w0 + h2.z * w2; acc1.z += h1.z * w1 + h3.z * w3;
        acc0.w += h0.w * w0 + h2.w * w2; acc1.w += h1.w * w1 + h3.w * w3;
    }
    for (; p < pend; p++) {
        unsigned e = epk[p];
        float4 hh = bf4tof4(Hp[(size_t)(e & 0x1FFFFu) * UPC + lane]);
        float w = (float)(e >> 17) * QS;
        acc0.x += hh.x * w; acc0.y += hh.y * w;
        acc0.z += hh.z * w; acc0.w += hh.w * w;
    }
    float4 acc;
    acc.x = acc0.x + acc1.x; acc.y = acc0.y + acc1.y;
    acc.z = acc0.z + acc1.z; acc.w = acc0.w + acc1.w;
    float sw = di * di;
    acc.x = acc.x * di + h.x * sw;
    acc.y = acc.y * di + h.y * sw;
    acc.z = acc.z * di + h.z * sw;
    acc.w = acc.w * di + h.w * sw;
    if (BIAS) {
        int fb = chunk * FPC + lane * 4;
        int isbf = flags[1];
        acc.x += ldf(bias, isbf, fb);
        acc.y += ldf(bias, isbf, fb + 1);
        acc.z += ldf(bias, isbf, fb + 2);
        acc.w += ldf(bias, isbf, fb + 3);
    }
    if (ELU) {
        acc.x = (acc.x > 0.0f) ? acc.x : expm1f(acc.x);
        acc.y = (acc.y > 0.0f) ? acc.y : expm1f(acc.y);
        acc.z = (acc.z > 0.0f) ? acc.z : expm1f(acc.z);
        acc.w = (acc.w > 0.0f) ? acc.w : expm1f(acc.w);
    }
    Op[(size_t)node * UPC + lane] = f4tobf4(acc);
}

// diagnostic fallback: if ws_size too small, emit sentinel 123.0
__global__ void k_sentinel(float* out, int n) {
    int i = blockIdx.x * blockDim.x + threadIdx.x;
    if (i < n) out[i] = 123.0f;
}

extern "C" void kernel_launch(void* const* d_in, const int* in_sizes, int n_in,
                              void* d_out, int out_size, void* d_ws, size_t ws_size,
                              hipStream_t stream) {
    const void* x  = d_in[0];
    const void* ei = d_in[1];
    const void* ea = d_in[2];
    const void* W1 = d_in[3];
    const void* b1 = d_in[4];
    const void* W2 = d_in[5];
    const void* b2 = d_in[6];
    const void* W3 = d_in[7];
    const void* b3 = d_in[8];
    float* out = (float*)d_out;

    // workspace layout (256B aligned)
    char* ws = (char*)d_ws;
    size_t off = 0;
    auto alloc = [&](size_t bytes) {
        off = (off + 255) & ~(size_t)255;
        size_t r = off;
        off += bytes;
        return r;
    };
    float* dinv    = (float*)(ws + alloc((size_t)N * 4));
    int*   counts  = (int*)  (ws + alloc((size_t)N * 4));
    int*   offsets = (int*)  (ws + alloc((size_t)N * 4));
    int*   bkt_cnt = (int*)  (ws + alloc((size_t)NBKT * 4));
    int*   bkt_off = (int*)  (ws + alloc((size_t)(NBKT + 1) * 4));
    int*   bkt_cur = (int*)  (ws + alloc((size_t)NBKT * 4));
    int*   flags   = (int*)  (ws + alloc(256));
    unsigned* epk  = (unsigned*)(ws + alloc((size_t)E * 4));
    // bf16 feature buffers (chunk-major planes): N*64*2 = 12.8MB each;
    // back-to-back so tmp (E*8 = 25.6MB) aliases bufA+bufB. tmp's last
    // read (k_fill) precedes bufA's first write (L1 GEMM).
    unsigned short* bufA = (unsigned short*)(ws + alloc((size_t)N * 64 * 2));
    unsigned short* bufB = (unsigned short*)(ws + alloc((size_t)N * 64 * 2));
    size_t need = off;
    int2* tmp = (int2*)bufA;

    if (ws_size < need) {
        hipLaunchKernelGGL(k_sentinel, dim3((N * 128 + 255) / 256), dim3(256), 0, stream,
                           out, N * 128);
        return;
    }

    const int gH = (E + HIST_EPB - 1) / HIST_EPB;   // 782
    const int gS = (E + SC_EPB - 1) / SC_EPB;       // 782
    const int gA32 = ((N + 255) / 256) * 8;         // 3128
    const int gA64 = ((N + 127) / 128) * 8;         // 6256

    hipLaunchKernelGGL(k_probe, dim3(1), dim3(256), 0, stream, ei, x, flags, bkt_cnt);
    hipLaunchKernelGGL(k_hist, dim3(gH), dim3(512), 0, stream, ei, flags, bkt_cnt);
    hipLaunchKernelGGL(k_bscan, dim3(1), dim3(256), 0, stream, bkt_cnt, bkt_off, bkt_cur);
    hipLaunchKernelGGL(k_scatter, dim3(gS), dim3(512), 0, stream, ei, flags, ea, bkt_cur, tmp);
    hipLaunchKernelGGL(k_nodecnt, dim3(NBKT), dim3(256), 0, stream, tmp, bkt_off,
                       counts, offsets, dinv);
    hipLaunchKernelGGL(k_fill, dim3(NBKT), dim3(256), 0, stream, tmp, bkt_off,
                       offsets, dinv, epk);

    // L1: t1 = x@W1 (bufA, F=32 cm); a1 = ELU(agg(t1)+b1) (bufB cm)
    hipLaunchKernelGGL((k_gemm<128, 32, 2, 4, 32, 1, true, false, false>),
                       dim3((N + 63) / 64), dim3(256), 0, stream, x, W1, nullptr, flags, bufA);
    hipLaunchKernelGGL((k_agg<32, true, true>), dim3(gA32), dim3(256), 0, stream,
                       (const uint2*)bufA, offsets, counts, epk, dinv, b1, flags, (uint2*)bufB);
    // L2: s2 = agg(a1) (bufA cm); h2 = ELU(s2@W2+b2) (bufB, F=64 cm)
    hipLaunchKernelGGL((k_agg<32, false, false>), dim3(gA32), dim3(256), 0, stream,
                       (const uint2*)bufB, offsets, counts, epk, dinv, nullptr, flags, (uint2*)bufA);
    hipLaunchKernelGGL((k_gemm<32, 64, 4, 4, 32, 2, true, true, true>),
                       dim3((N + 63) / 64), dim3(256), 0, stream, bufA, W2, b2, flags, bufB);
    // L3: s3 = agg(h2) (bufA, F=64 cm); out = s3@W3+b3 (d_out fp32 row-major)
    hipLaunchKernelGGL((k_agg<64, false, false>), dim3(gA64), dim3(256), 0, stream,
                       (const uint2*)bufB, offsets, counts, epk, dinv, nullptr, flags, (uint2*)bufA);
    hipLaunchKernelGGL((k_gemm<64, 128, 4, 8, 32, 2, false, true, false>),
                       dim3((N + 63) / 64), dim3(256), 0, stream, bufA, W3, b3, flags, out);
}

// Round 13
// 425.015 us; speedup vs baseline: 1.5834x; 1.5834x over previous
//
#include <hip/hip_runtime.h>
#include <hip/hip_bf16.h>

// GCN 3-layer: gcn_norm -> (GCNConv, ELU) x2 -> GCNConv
// N=100000, E=3200000, dims 128->32->64->128.
// agg is linear => aggregate in the SMALLER feature dim per layer:
//   L1: t1 = x@W1 (128->32); a1 = ELU(agg(t1) + b1)          [gather F=32]
//   L2: s2 = agg(a1);        h2 = ELU(s2@W2 + b2)            [gather F=32]
//   L3: s3 = agg(h2);        out = s3@W3 + b3                [gather F=64]
//
// CSR build: bucketed 2-level counting sort (k_hist -> k_bscan ->
// k_scatter -> k_nodecnt -> k_fill).
// epk[e] = src(17b) | q15(dinv[src]*ew)<<17  (4B/edge, precomputed w').
//
// LESSONS:
//  - r2: LDS f32 atomicAdd agg = 12x slower. Never E*F-scale ds_add.
//  - r3: agg near compulsory-traffic ceiling; bytes are the lever.
//  - r4: bf16 intermediate buffers (storage only, fp32 accum) -> -93us.
//  - r5/r6: scatter fixed via batch-load-then-process + 782 blocks.
//  - r8: dinv[src] inside agg loop = wash; keep hot loops minimal.
//  - r9: 4B epk w/ precomputed q15(dinv*ew): aggs off the top.
//  - r10/r11: GEMM bank-conflict map swap (trow=t%TROWS) + KC=32
//    chunked staging: GEMMs 57us -> off the top-5. 452.9 -> 425.4us.
//  - r12 (REVERTED): XCD feature-chunking (8 planes, chunk=blockIdx&7)
//    DID cut HBM fetch 158->64MB (planes L2-resident as predicted) but
//    agg64 52.7->133.6us: with 2 lanes/node a wave's gather instr spans
//    32 distinct edges x 16B = ~32 cache-line requests/instr (vs 4x128B
//    contiguous) -> vmem request-rate-bound (VALU 25%, BW 7%, occ 61%,
//    nothing saturated) + 8x epk re-reads + degree divergence over 32
//    nodes/wave. Chunking trades HBM bytes for L2 request count — bad
//    trade at 42% BW. Keep >=16-lane-contiguous gathers.
//  - r11 state: agg64 co-limited VALU 52% + BW 42% (~94% combined) —
//    near this structure's ceiling.
// Inputs: fp32 (probed vs bf16), edge_index i64 (probed vs i32). Output fp32.

constexpr int N = 100000;
constexpr int E = 3200000;

constexpr int BSHIFT = 7;
constexpr int BSIZE = 128;                       // nodes per bucket
constexpr int NBKT = (N + BSIZE - 1) / BSIZE;    // 782

constexpr float FIX_SCALE = 16777216.0f;         // 2^24
constexpr float Q15 = 32768.0f;

constexpr int HIST_EPB = 4096;                   // edges per block, hist
constexpr int SC_EPB = 4096;                     // edges per block, scatter

__device__ __forceinline__ float ldf(const void* p, int isbf, size_t i) {
    return isbf ? __bfloat162float(((const __hip_bfloat16*)p)[i])
                : ((const float*)p)[i];
}

__device__ __forceinline__ int ld_idx(const void* ei, int is64, size_t pos) {
    return is64 ? (int)((const long long*)ei)[pos] : ((const int*)ei)[pos];
}

// --- bf16x4 pack/unpack (manual RNE, no API dependence) ---
__device__ __forceinline__ float4 bf4tof4(uint2 u) {
    float4 r;
    r.x = __uint_as_float(u.x << 16);
    r.y = __uint_as_float(u.x & 0xffff0000u);
    r.z = __uint_as_float(u.y << 16);
    r.w = __uint_as_float(u.y & 0xffff0000u);
    return r;
}
__device__ __forceinline__ unsigned short f2bf(float f) {
    unsigned u = __float_as_uint(f);
    unsigned rnd = 0x7fffu + ((u >> 16) & 1u);
    return (unsigned short)((u + rnd) >> 16);
}
__device__ __forceinline__ unsigned packbf2(float a, float b) {
    return (unsigned)f2bf(a) | ((unsigned)f2bf(b) << 16);
}
__device__ __forceinline__ uint2 f4tobf4(float4 v) {
    uint2 r;
    r.x = packbf2(v.x, v.y);
    r.y = packbf2(v.z, v.w);
    return r;
}

// flags[0] = is64 (edge_index), flags[1] = isbf (float tensors)
// also zeroes the bucket-count array (runs before k_hist on the stream)
__global__ void k_probe(const void* ei, const void* x, int* flags, int* bkt_cnt) {
    __shared__ int bad64, bigcnt;
    int t = threadIdx.x;
    if (t == 0) { bad64 = 0; bigcnt = 0; }
    __syncthreads();
    long long v = ((const long long*)ei)[t];
    if (v < 0 || v >= (long long)N) atomicAdd(&bad64, 1);
    const unsigned short* u = (const unsigned short*)x;
    int big = 0;
    for (int i = t * 16; i < t * 16 + 16; i++) {
        int e = (u[i] >> 7) & 0xFF;
        if (e >= 133) big++;
    }
    atomicAdd(&bigcnt, big);
    for (int i = t; i < NBKT; i += 256) bkt_cnt[i] = 0;
    __syncthreads();
    if (t == 0) { flags[0] = (bad64 == 0) ? 1 : 0; flags[1] = (bigcnt < 40) ? 1 : 0; }
}

// bucket histogram: batch-load targets into registers, then LDS atomics,
// one global atomic per (block,bucket)
__global__ __launch_bounds__(512) void k_hist(const void* ei, const int* flags,
                                              int* bkt_cnt) {
    constexpr int EPT = HIST_EPB / 512;          // 8
    __shared__ int h[NBKT];
    int t = threadIdx.x;
    for (int i = t; i < NBKT; i += 512) h[i] = 0;
    __syncthreads();
    int is64 = flags[0];
    size_t eb = (size_t)blockIdx.x * HIST_EPB;
    int nb = (int)min((size_t)HIST_EPB, (size_t)E - eb);
    int cc[EPT];
#pragma unroll
    for (int k = 0; k < EPT; k++) {
        int idx = t + k * 512;
        cc[k] = (idx < nb) ? ld_idx(ei, is64, (size_t)E + eb + idx) : -1;
    }
#pragma unroll
    for (int k = 0; k < EPT; k++)
        if (cc[k] >= 0) atomicAdd(&h[cc[k] >> BSHIFT], 1);
    __syncthreads();
    for (int i = t; i < NBKT; i += 512) {
        int v = h[i];
        if (v) atomicAdd(&bkt_cnt[i], v);
    }
}

// single-block exclusive scan over NBKT buckets -> bkt_off, bkt_cur
__global__ void k_bscan(const int* bkt_cnt, int* bkt_off, int* bkt_cur) {
    __shared__ int s[256];
    int t = threadIdx.x;
    int v[4]; int sum = 0;
#pragma unroll
    for (int j = 0; j < 4; j++) {
        int i = t * 4 + j;
        v[j] = (i < NBKT) ? bkt_cnt[i] : 0;
        sum += v[j];
    }
    s[t] = sum; __syncthreads();
    for (int st = 1; st < 256; st <<= 1) {
        int add = (t >= st) ? s[t - st] : 0;
        __syncthreads();
        s[t] += add;
        __syncthreads();
    }
    int excl = s[t] - sum;
#pragma unroll
    for (int j = 0; j < 4; j++) {
        int i = t * 4 + j;
        if (i < NBKT) { bkt_off[i] = excl; bkt_cur[i] = excl; excl += v[j]; }
    }
    if (t == 0) bkt_off[NBKT] = E;
}

// bucket-sort edges into tmp[]: batch-load (r,c,w) into registers ONCE,
// then per-block LDS histogram + run reservation + placement, all from
// registers. tmp entry: .x = r | (c&127)<<17  (r<2^17), .y = w bits
__global__ __launch_bounds__(512) void k_scatter(const void* ei, const int* flags,
                                                 const void* ew, int* bkt_cur,
                                                 int2* tmp) {
    constexpr int EPT = SC_EPB / 512;            // 8
    __shared__ int h[NBKT];
    __shared__ int base_s[NBKT];
    int t = threadIdx.x;
    for (int i = t; i < NBKT; i += 512) h[i] = 0;
    __syncthreads();
    int is64 = flags[0], isbf = flags[1];
    size_t eb = (size_t)blockIdx.x * SC_EPB;
    int nb = (int)min((size_t)SC_EPB, (size_t)E - eb);
    int rr[EPT], cc[EPT]; float ww[EPT];
    // batched, coalesced, independent loads; single drain
#pragma unroll
    for (int k = 0; k < EPT; k++) {
        int idx = t + k * 512;
        if (idx < nb) {
            size_t e = eb + idx;
            rr[k] = ld_idx(ei, is64, e);
            cc[k] = ld_idx(ei, is64, (size_t)E + e);
            ww[k] = ldf(ew, isbf, e);
        } else {
            rr[k] = 0; cc[k] = -1; ww[k] = 0.f;
        }
    }
    // pass 1: local histogram (registers -> LDS atomics, pipelined)
#pragma unroll
    for (int k = 0; k < EPT; k++)
        if (cc[k] >= 0) atomicAdd(&h[cc[k] >> BSHIFT], 1);
    __syncthreads();
    // reserve a dense run per bucket
    for (int i = t; i < NBKT; i += 512) {
        int v = h[i];
        base_s[i] = v ? atomicAdd(&bkt_cur[i], v) : 0;
    }
    __syncthreads();
    for (int i = t; i < NBKT; i += 512) h[i] = 0;
    __syncthreads();
    // pass 2: place edges within reserved runs (registers -> global)
#pragma unroll
    for (int k = 0; k < EPT; k++) {
        if (cc[k] >= 0) {
            int b = cc[k] >> BSHIFT;
            int loc = atomicAdd(&h[b], 1);
            int pos = base_s[b] + loc;
            tmp[pos] = make_int2(rr[k] | ((cc[k] & (BSIZE - 1)) << 17),
                                 __float_as_int(ww[k]));
        }
    }
}

// per bucket: node counts + fixed-point weight sums (LDS int atomics),
// 128-wide LDS scan -> offsets; dinv = rsqrt(1 + wsum) (bit-identical
// to the original packed scheme)
__global__ __launch_bounds__(256) void k_nodecnt(const int2* __restrict__ tmp,
                                                 const int* __restrict__ bkt_off,
                                                 int* __restrict__ counts,
                                                 int* __restrict__ offsets,
                                                 float* __restrict__ dinv) {
    __shared__ int cnt_s[BSIZE];
    __shared__ unsigned int wfx_s[BSIZE];
    __shared__ int sc_s[BSIZE];
    int t = threadIdx.x;
    int b = blockIdx.x;
    if (t < BSIZE) { cnt_s[t] = 0; wfx_s[t] = 0u; }
    __syncthreads();
    int s0 = bkt_off[b], s1 = bkt_off[b + 1];
    for (int p = s0 + t; p < s1; p += 256) {
        int2 ev = tmp[p];
        int c7 = (int)(((unsigned)ev.x) >> 17);
        float w = __int_as_float(ev.y);
        atomicAdd(&cnt_s[c7], 1);
        atomicAdd(&wfx_s[c7], (unsigned)__float2uint_rn(w * FIX_SCALE));
    }
    __syncthreads();
    if (t < BSIZE) sc_s[t] = cnt_s[t];
    __syncthreads();
    for (int st = 1; st < BSIZE; st <<= 1) {
        int add = (t < BSIZE && t >= st) ? sc_s[t - st] : 0;
        __syncthreads();
        if (t < BSIZE) sc_s[t] += add;
        __syncthreads();
    }
    if (t < BSIZE) {
        int node = b * BSIZE + t;
        if (node < N) {
            int c = cnt_s[t];
            offsets[node] = s0 + sc_s[t] - c;   // bucket base + exclusive
            counts[node] = c;
            float deg = 1.0f + (float)wfx_s[t] * (1.0f / FIX_SCALE);
            dinv[node] = rsqrtf(deg);
        }
    }
}

// per bucket: fill 4B CSR epk[pos] = src | q15(dinv[src]*ew)<<17.
// w' = dinv*ew < 1 strictly (dinv<=1, ew<1) so q15 fits 15 bits
// (clamped at 32767 for the rounding edge case). dinv table reads are
// random but 400KB L2-resident. Destination range is the bucket's
// contiguous slice of epk -> block-private, dense.
__global__ __launch_bounds__(256) void k_fill(const int2* __restrict__ tmp,
                                              const int* __restrict__ bkt_off,
                                              const int* __restrict__ offsets,
                                              const float* __restrict__ dinv,
                                              unsigned* __restrict__ epk) {
    __shared__ int lcur[BSIZE];
    int t = threadIdx.x;
    int b = blockIdx.x;
    if (t < BSIZE) {
        int node = b * BSIZE + t;
        lcur[t] = (node < N) ? offsets[node] : 0;
    }
    __syncthreads();
    int s0 = bkt_off[b], s1 = bkt_off[b + 1];
    for (int p = s0 + t; p < s1; p += 256) {
        int2 ev = tmp[p];
        unsigned px = (unsigned)ev.x;
        int r = (int)(px & 0x1FFFFu);
        int c7 = (int)(px >> 17);
        float w = __int_as_float(ev.y);
        float nr = dinv[r] * w;
        unsigned q = __float2uint_rn(nr * Q15);
        if (q > 32767u) q = 32767u;
        int pos = atomicAdd(&lcur[c7], 1);
        epk[pos] = (unsigned)r | (q << 17);
    }
}

// --- register-blocked GEMM: H[N,FOUT] = X[N,FIN] @ W[FIN,FOUT] (+b, ELU)
// XMODE: 1 = external input (runtime fp32/bf16 probe), 2 = internal bf16.
// OBF: write bf16 (internal buffer) vs fp32 (final output).
// KC: k-chunk for LDS staging (cuts LDS 48.5->24/12KB; occupancy 3->4-6
// blocks/CU). Thread map trow=t%TROWS (NOT t%TCOLS): a wave's wl reads
// become 16-lane broadcasts on disjoint banks (was 4-way conflict,
// 3.4M cycles); xt reads 2-way (free).
template <int FIN, int FOUT, int TM, int TN, int KC, int XMODE, bool OBF,
          bool BIAS, bool ELU>
__global__ __launch_bounds__(256) void k_gemm(const void* __restrict__ X,
                                              const void* __restrict__ W,
                                              const void* __restrict__ bias,
                                              const int* __restrict__ flags,
                                              void* __restrict__ H) {
    constexpr int TCOLS = FOUT / TN;
    constexpr int TROWS = 256 / TCOLS;
    constexpr int BR = TROWS * TM;
    __shared__ float wl[KC * FOUT];
    __shared__ float xt[KC][BR + 1];
    int t = threadIdx.x;
    int isbf = flags[1];
    int base = blockIdx.x * BR;
    int trow = t % TROWS, tcol = t / TROWS;   // bank-conflict-free map
    int r0 = trow * TM, c0 = tcol * TN;
    float acc[TM][TN] = {};

    for (int kc = 0; kc < FIN; kc += KC) {
        if (kc) __syncthreads();              // previous chunk fully read
        // stage W rows [kc, kc+KC)
        if (!isbf) {
            const float4* W4 = (const float4*)W;
            float4* wl4 = (float4*)wl;
            for (int i = t; i < KC * FOUT / 4; i += 256)
                wl4[i] = W4[(size_t)kc * FOUT / 4 + i];
        } else {
            for (int i = t; i < KC * FOUT; i += 256)
                wl[i] = __bfloat162float(((const __hip_bfloat16*)W)[(size_t)kc * FOUT + i]);
        }
        // stage X columns [kc, kc+KC), transposed into xt[k][row]
        if (XMODE == 2) {
            const uint2* X2 = (const uint2*)X;
            for (int i = t; i < BR * KC / 4; i += 256) {
                int row = i / (KC / 4);
                int kq = i % (KC / 4);
                int node = base + row;
                uint2 u = make_uint2(0u, 0u);
                if (node < N) u = X2[(size_t)node * (FIN / 4) + kc / 4 + kq];
                float4 v = bf4tof4(u);
                int k = kq * 4;
                xt[k][row] = v.x; xt[k + 1][row] = v.y;
                xt[k + 2][row] = v.z; xt[k + 3][row] = v.w;
            }
        } else if (!isbf) {
            const float4* X4 = (const float4*)X;
            for (int i = t; i < BR * KC / 4; i += 256) {
                int row = i / (KC / 4);
                int kq = i % (KC / 4);
                int node = base + row;
                float4 v = make_float4(0.f, 0.f, 0.f, 0.f);
                if (node < N) v = X4[(size_t)node * (FIN / 4) + kc / 4 + kq];
                int k = kq * 4;
                xt[k][row] = v.x; xt[k + 1][row] = v.y;
                xt[k + 2][row] = v.z; xt[k + 3][row] = v.w;
            }
        } else {
            for (int i = t; i < BR * KC; i += 256) {
                int row = i / KC, k = i % KC;
                int node = base + row;
                float v = (node < N)
                    ? __bfloat162float(((const __hip_bfloat16*)X)[(size_t)node * FIN + kc + k])
                    : 0.f;
                xt[k][row] = v;
            }
        }
        __syncthreads();

#pragma unroll 4
        for (int k = 0; k < KC; k++) {
            float a[TM], b[TN];
#pragma unroll
            for (int m = 0; m < TM; m++) a[m] = xt[k][r0 + m];
#pragma unroll
            for (int n = 0; n < TN; n++) b[n] = wl[k * FOUT + c0 + n];
#pragma unroll
            for (int m = 0; m < TM; m++)
#pragma unroll
                for (int n = 0; n < TN; n++) acc[m][n] += a[m] * b[n];
        }
    }

#pragma unroll
    for (int m = 0; m < TM; m++) {
        int node = base + r0 + m;
        if (node >= N) continue;
        float vv[TN];
#pragma unroll
        for (int n = 0; n < TN; n++) {
            float v = acc[m][n];
            if (BIAS) v += ldf(bias, isbf, c0 + n);
            if (ELU) v = (v > 0.0f) ? v : expm1f(v);
            vv[n] = v;
        }
        if (OBF) {
            unsigned* Hrow = (unsigned*)((unsigned short*)H + (size_t)node * FOUT + c0);
#pragma unroll
            for (int n = 0; n < TN; n += 2)
                Hrow[n / 2] = packbf2(vv[n], vv[n + 1]);
        } else {
            float* Hrow = (float*)H + (size_t)node * FOUT + c0;
#pragma unroll
            for (int n = 0; n < TN; n += 4)
                *(float4*)(Hrow + n) = make_float4(vv[n], vv[n + 1], vv[n + 2], vv[n + 3]);
        }
    }
}

// --- aggregation: out[n] = di*Σ_e w'_e*H[src_e] + di^2*H[n] (+b, ELU)
// epk 4B/edge: src(17b) | q15(w'=dinv[src]*ew)<<17, w' precomputed in
// k_fill -- no per-edge dinv load here (r8 lesson). Node-parallel, LPN
// lanes per node, bf16 feature rows (>=16-lane-contiguous gathers --
// r12 lesson). Unroll 8 + software pipeline; fp32 accumulation.
template <int F, bool BIAS, bool ELU>
__global__ __launch_bounds__(256) void k_agg(const uint2* __restrict__ Hb,
                                             const int* __restrict__ offsets,
                                             const int* __restrict__ counts,
                                             const unsigned* __restrict__ epk,
                                             const float* __restrict__ dinv,
                                             const void* __restrict__ bias,
                                             const int* __restrict__ flags,
                                             uint2* __restrict__ outb) {
    constexpr int LPN = F / 4;        // lanes per node (uint2 per lane)
    constexpr int NPB = 256 / LPN;    // nodes per block
    constexpr float QS = 1.0f / Q15;
    int t = threadIdx.x;
    int lane = t % LPN;
    int g = t / LPN;
    int node = blockIdx.x * NPB + g;
    if (node >= N) return;
    float di = dinv[node];
    float4 h = bf4tof4(Hb[(size_t)node * LPN + lane]);
    float4 acc0 = make_float4(0.f, 0.f, 0.f, 0.f);
    float4 acc1 = make_float4(0.f, 0.f, 0.f, 0.f);
    int p = offsets[node];
    int pend = p + counts[node];

    unsigned eA[8];
    bool have = (p + 8 <= pend);
    if (have) {
#pragma unroll
        for (int j = 0; j < 8; j++) eA[j] = epk[p + j];
    }
    while (have) {
        // issue 8 independent gathers (8B each)
        uint2 gg[8];
#pragma unroll
        for (int j = 0; j < 8; j++)
            gg[j] = Hb[(size_t)(eA[j] & 0x1FFFFu) * LPN + lane];
        float w[8];
#pragma unroll
        for (int j = 0; j < 8; j++) w[j] = (float)(eA[j] >> 17) * QS;
        p += 8;
        bool nxt = (p + 8 <= pend);
        unsigned eB[8];
        if (nxt) {
#pragma unroll
            for (int j = 0; j < 8; j++) eB[j] = epk[p + j];
        }
        // accumulate current batch (drains gather vmcnt; next epk loads
        // already in flight)
#pragma unroll
        for (int j = 0; j < 8; j += 2) {
            float4 g0 = bf4tof4(gg[j]);
            float4 g1 = bf4tof4(gg[j + 1]);
            acc0.x += g0.x * w[j]; acc0.y += g0.y * w[j];
            acc0.z += g0.z * w[j]; acc0.w += g0.w * w[j];
            acc1.x += g1.x * w[j + 1]; acc1.y += g1.y * w[j + 1];
            acc1.z += g1.z * w[j + 1]; acc1.w += g1.w * w[j + 1];
        }
#pragma unroll
        for (int j = 0; j < 8; j++) eA[j] = eB[j];
        have = nxt;
    }
    // tail: 4-wide then scalar
    for (; p + 4 <= pend; p += 4) {
        unsigned e0 = epk[p], e1 = epk[p + 1], e2 = epk[p + 2], e3 = epk[p + 3];
        float4 h0 = bf4tof4(Hb[(size_t)(e0 & 0x1FFFFu) * LPN + lane]);
        float4 h1 = bf4tof4(Hb[(size_t)(e1 & 0x1FFFFu) * LPN + lane]);
        float4 h2 = bf4tof4(Hb[(size_t)(e2 & 0x1FFFFu) * LPN + lane]);
        float4 h3 = bf4tof4(Hb[(size_t)(e3 & 0x1FFFFu) * LPN + lane]);
        float w0 = (float)(e0 >> 17) * QS;
        float w1 = (float)(e1 >> 17) * QS;
        float w2 = (float)(e2 >> 17) * QS;
        float w3 = (float)(e3 >> 17) * QS;
        acc0.x += h0.x * w0 + h2.x * w2; acc1.x += h1.x * w1 + h3.x * w3;
        acc0.y += h0.y * w0 + h2.y * w2; acc1.y += h1.y * w1 + h3.y * w3;
        acc0.z += h0.z * w0 + h2.z * w2; acc1.z += h1.z * w1 + h3.z * w3;
        acc0.w += h0.w * w0 + h2.w * w2; acc1.w += h1.w * w1 + h3.w * w3;
    }
    for (; p < pend; p++) {
        unsigned e = epk[p];
        float4 hh = bf4tof4(Hb[(size_t)(e & 0x1FFFFu) * LPN + lane]);
        float w = (float)(e >> 17) * QS;
        acc0.x += hh.x * w; acc0.y += hh.y * w;
        acc0.z += hh.z * w; acc0.w += hh.w * w;
    }
    float4 acc;
    acc.x = acc0.x + acc1.x; acc.y = acc0.y + acc1.y;
    acc.z = acc0.z + acc1.z; acc.w = acc0.w + acc1.w;
    float sw = di * di;
    acc.x = acc.x * di + h.x * sw;
    acc.y = acc.y * di + h.y * sw;
    acc.z = acc.z * di + h.z * sw;
    acc.w = acc.w * di + h.w * sw;
    if (BIAS) {
        int fb = lane * 4;
        int isbf = flags[1];
        acc.x += ldf(bias, isbf, fb);
        acc.y += ldf(bias, isbf, fb + 1);
        acc.z += ldf(bias, isbf, fb + 2);
        acc.w += ldf(bias, isbf, fb + 3);
    }
    if (ELU) {
        acc.x = (acc.x > 0.0f) ? acc.x : expm1f(acc.x);
        acc.y = (acc.y > 0.0f) ? acc.y : expm1f(acc.y);
        acc.z = (acc.z > 0.0f) ? acc.z : expm1f(acc.z);
        acc.w = (acc.w > 0.0f) ? acc.w : expm1f(acc.w);
    }
    outb[(size_t)node * LPN + lane] = f4tobf4(acc);
}

// diagnostic fallback: if ws_size too small, emit sentinel 123.0
__global__ void k_sentinel(float* out, int n) {
    int i = blockIdx.x * blockDim.x + threadIdx.x;
    if (i < n) out[i] = 123.0f;
}

extern "C" void kernel_launch(void* const* d_in, const int* in_sizes, int n_in,
                              void* d_out, int out_size, void* d_ws, size_t ws_size,
                              hipStream_t stream) {
    const void* x  = d_in[0];
    const void* ei = d_in[1];
    const void* ea = d_in[2];
    const void* W1 = d_in[3];
    const void* b1 = d_in[4];
    const void* W2 = d_in[5];
    const void* b2 = d_in[6];
    const void* W3 = d_in[7];
    const void* b3 = d_in[8];
    float* out = (float*)d_out;

    // workspace layout (256B aligned)
    char* ws = (char*)d_ws;
    size_t off = 0;
    auto alloc = [&](size_t bytes) {
        off = (off + 255) & ~(size_t)255;
        size_t r = off;
        off += bytes;
        return r;
    };
    float* dinv    = (float*)(ws + alloc((size_t)N * 4));
    int*   counts  = (int*)  (ws + alloc((size_t)N * 4));
    int*   offsets = (int*)  (ws + alloc((size_t)N * 4));
    int*   bkt_cnt = (int*)  (ws + alloc((size_t)NBKT * 4));
    int*   bkt_off = (int*)  (ws + alloc((size_t)(NBKT + 1) * 4));
    int*   bkt_cur = (int*)  (ws + alloc((size_t)NBKT * 4));
    int*   flags   = (int*)  (ws + alloc(256));
    unsigned* epk  = (unsigned*)(ws + alloc((size_t)E * 4));
    // bf16 feature buffers: N*64*2 = 12.8MB each; allocated back-to-back
    // (12.8MB is 256B-aligned) so tmp (E*8 = 25.6MB) aliases bufA+bufB.
    // tmp's last read (k_fill) precedes bufA's first write (L1 GEMM).
    unsigned short* bufA = (unsigned short*)(ws + alloc((size_t)N * 64 * 2));
    unsigned short* bufB = (unsigned short*)(ws + alloc((size_t)N * 64 * 2));
    size_t need = off;
    int2* tmp = (int2*)bufA;

    if (ws_size < need) {
        hipLaunchKernelGGL(k_sentinel, dim3((N * 128 + 255) / 256), dim3(256), 0, stream,
                           out, N * 128);
        return;
    }

    const int gH = (E + HIST_EPB - 1) / HIST_EPB;   // 782
    const int gS = (E + SC_EPB - 1) / SC_EPB;       // 782

    hipLaunchKernelGGL(k_probe, dim3(1), dim3(256), 0, stream, ei, x, flags, bkt_cnt);
    hipLaunchKernelGGL(k_hist, dim3(gH), dim3(512), 0, stream, ei, flags, bkt_cnt);
    hipLaunchKernelGGL(k_bscan, dim3(1), dim3(256), 0, stream, bkt_cnt, bkt_off, bkt_cur);
    hipLaunchKernelGGL(k_scatter, dim3(gS), dim3(512), 0, stream, ei, flags, ea, bkt_cur, tmp);
    hipLaunchKernelGGL(k_nodecnt, dim3(NBKT), dim3(256), 0, stream, tmp, bkt_off,
                       counts, offsets, dinv);
    hipLaunchKernelGGL(k_fill, dim3(NBKT), dim3(256), 0, stream, tmp, bkt_off,
                       offsets, dinv, epk);

    // L1: t1 = x@W1 (bufA, F=32 bf16); a1 = ELU(agg(t1)+b1) (bufB bf16)
    hipLaunchKernelGGL((k_gemm<128, 32, 2, 4, 32, 1, true, false, false>),
                       dim3((N + 63) / 64), dim3(256), 0, stream, x, W1, nullptr, flags, bufA);
    hipLaunchKernelGGL((k_agg<32, true, true>), dim3((N + 31) / 32), dim3(256), 0, stream,
                       (const uint2*)bufA, offsets, counts, epk, dinv, b1, flags, (uint2*)bufB);
    // L2: s2 = agg(a1) (bufA bf16); h2 = ELU(s2@W2+b2) (bufB, F=64 bf16)
    hipLaunchKernelGGL((k_agg<32, false, false>), dim3((N + 31) / 32), dim3(256), 0, stream,
                       (const uint2*)bufB, offsets, counts, epk, dinv, nullptr, flags, (uint2*)bufA);
    hipLaunchKernelGGL((k_gemm<32, 64, 4, 4, 32, 2, true, true, true>),
                       dim3((N + 63) / 64), dim3(256), 0, stream, bufA, W2, b2, flags, bufB);
    // L3: s3 = agg(h2) (bufA, F=64 bf16); out = s3@W3+b3 (d_out fp32)
    hipLaunchKernelGGL((k_agg<64, false, false>), dim3((N + 15) / 16), dim3(256), 0, stream,
                       (const uint2*)bufB, offsets, counts, epk, dinv, nullptr, flags, (uint2*)bufA);
    hipLaunchKernelGGL((k_gemm<64, 128, 4, 8, 32, 2, false, true, false>),
                       dim3((N + 63) / 64), dim3(256), 0, stream, bufA, W3, b3, flags, out);
}